// Round 1
// baseline (5378.608 us; speedup 1.0000x reference)
//
#include <hip/hip_runtime.h>

#define N_ATOMS   50000
#define N_EDGES   1600000
#define N_ANGLES  1500000

__device__ __forceinline__ float silu_f(float x) {
    // x * sigmoid(x) = x / (1 + exp(-x)); fast div + hw exp
    return __fdividef(x, 1.0f + __expf(-x));
}

// ---------------------------------------------------------------------------
// Edge precompute: Rij[e] = (s/d, (s/d^2)*vec)  as float4
// ---------------------------------------------------------------------------
__global__ __launch_bounds__(256) void edge_kernel(
    const float* __restrict__ distances, const float* __restrict__ sw,
    const float* __restrict__ vec, float4* __restrict__ Rij)
{
    int e = (int)blockIdx.x * 256 + (int)threadIdx.x;
    if (e >= N_EDGES) return;
    const float d   = distances[e];
    const float s   = sw[e];
    const float inv = 1.0f / d;
    const float sij = s * inv;
    const float c   = sij * inv;
    const float vx = vec[3*e+0], vy = vec[3*e+1], vz = vec[3*e+2];
    Rij[e] = make_float4(sij, c*vx, c*vy, c*vz);
}

// ---------------------------------------------------------------------------
// Angle kernel: one thread per angle.
//   theta = dot(Rij[src], Rij[dst])
//   h0 = silu(theta*W0[0] + W0[1+s] + W0[17+d] + b0)   (one-hot collapse)
//   two MLPs share W3:  G = (hfin1 + hfin2) @ W3 + 2*b3
//   out[ca] += G * theta   (64 f32 atomics)
// Activations live in LDS transposed [64][256]: bank = tid%32 -> conflict-free.
// Weights are read at wave-uniform addresses -> compiler scalarizes (s_load).
// No __syncthreads needed: each thread only touches its own LDS column.
// ---------------------------------------------------------------------------
__global__ __launch_bounds__(256, 2) void angle_kernel(
    const int* __restrict__ a_src, const int* __restrict__ a_dst,
    const int* __restrict__ a_ca, const float4* __restrict__ Rij,
    const int* __restrict__ edge_dst, const int* __restrict__ species,
    const float* __restrict__ W0, const float* __restrict__ b0,
    const float* __restrict__ W1, const float* __restrict__ b1,
    const float* __restrict__ W2, const float* __restrict__ b2,
    const float* __restrict__ W3, const float* __restrict__ b3,
    float* __restrict__ out)
{
    __shared__ float hbuf[64 * 256];   // [k][tid], 64 KB
    const int tid = (int)threadIdx.x;
    int a = (int)blockIdx.x * 256 + tid;
    const bool active = (a < N_ANGLES);
    if (!active) a = N_ANGLES - 1;     // clamp: loads stay in-bounds, atomic masked

    const int se = a_src[a];
    const int de = a_dst[a];
    const int ca = a_ca[a];
    const float4 Rs = Rij[se];
    const float4 Rd = Rij[de];
    const float theta = Rs.x*Rd.x + Rs.y*Rd.y + Rs.z*Rd.z + Rs.w*Rd.w;
    const int ssp = species[edge_dst[se]];
    const int dsp = species[edge_dst[de]];

    float hs[64];   // holds MLP-1 final hidden across the m=1 pass

    #pragma unroll 1
    for (int m = 0; m < 2; ++m) {
        const int r1 = m ? dsp : ssp;
        const int r2 = m ? ssp : dsp;
        const float* __restrict__ rA = W0 + (1  + r1) * 64;
        const float* __restrict__ rB = W0 + (17 + r2) * 64;

        // layer 0 (one-hot collapsed)
        #pragma unroll
        for (int j = 0; j < 64; ++j) {
            float x = fmaf(theta, W0[j], rA[j] + rB[j] + b0[j]);
            hbuf[j*256 + tid] = silu_f(x);
        }

        // layers 1 and 2: dense 64x64, acc in registers, weights scalar-loaded
        #pragma unroll 1
        for (int l = 0; l < 2; ++l) {
            const float* __restrict__ W  = l ? W2 : W1;
            const float* __restrict__ bb = l ? b2 : b1;
            float nxt[64];
            #pragma unroll
            for (int j = 0; j < 64; ++j) nxt[j] = bb[j];
            #pragma unroll 2
            for (int k = 0; k < 64; ++k) {
                const float hk = hbuf[k*256 + tid];
                const float* __restrict__ wr = W + k*64;
                #pragma unroll
                for (int j = 0; j < 64; ++j) nxt[j] = fmaf(hk, wr[j], nxt[j]);
            }
            #pragma unroll
            for (int j = 0; j < 64; ++j) hbuf[j*256 + tid] = silu_f(nxt[j]);
        }

        if (m == 0) {
            #pragma unroll
            for (int j = 0; j < 64; ++j) hs[j] = hbuf[j*256 + tid];
        } else {
            #pragma unroll
            for (int j = 0; j < 64; ++j) hbuf[j*256 + tid] += hs[j];
        }
    }

    // shared final layer: G = (hfin1+hfin2) @ W3 + 2*b3
    float g[64];
    #pragma unroll
    for (int j = 0; j < 64; ++j) g[j] = 2.0f * b3[j];
    #pragma unroll 2
    for (int k = 0; k < 64; ++k) {
        const float hk = hbuf[k*256 + tid];
        const float* __restrict__ wr = W3 + k*64;
        #pragma unroll
        for (int j = 0; j < 64; ++j) g[j] = fmaf(hk, wr[j], g[j]);
    }

    if (active) {
        float* op = out + (size_t)ca * 64;
        #pragma unroll
        for (int j = 0; j < 64; ++j) atomicAdd(op + j, g[j] * theta);
    }
}

extern "C" void kernel_launch(void* const* d_in, const int* in_sizes, int n_in,
                              void* d_out, int out_size, void* d_ws, size_t ws_size,
                              hipStream_t stream) {
    const int*   species   = (const int*)  d_in[0];
    const int*   edge_dst  = (const int*)  d_in[1];
    const float* distances = (const float*)d_in[2];
    const float* sw        = (const float*)d_in[3];
    const float* vec       = (const float*)d_in[4];
    const int*   a_src     = (const int*)  d_in[5];
    const int*   a_dst     = (const int*)  d_in[6];
    const int*   a_ca      = (const int*)  d_in[7];
    const float* W0 = (const float*)d_in[8];
    const float* b0 = (const float*)d_in[9];
    const float* W1 = (const float*)d_in[10];
    const float* b1 = (const float*)d_in[11];
    const float* W2 = (const float*)d_in[12];
    const float* b2 = (const float*)d_in[13];
    const float* W3 = (const float*)d_in[14];
    const float* b3 = (const float*)d_in[15];
    float* out = (float*)d_out;

    float4* Rij = (float4*)d_ws;   // 1.6M * 16B = 25.6 MB scratch

    hipMemsetAsync(d_out, 0, (size_t)out_size * sizeof(float), stream);

    edge_kernel<<<(N_EDGES + 255) / 256, 256, 0, stream>>>(distances, sw, vec, Rij);

    angle_kernel<<<(N_ANGLES + 255) / 256, 256, 0, stream>>>(
        a_src, a_dst, a_ca, Rij, edge_dst, species,
        W0, b0, W1, b1, W2, b2, W3, b3, out);
}

// Round 2
// 3626.052 us; speedup vs baseline: 1.4833x; 1.4833x over previous
//
#include <hip/hip_runtime.h>

#define N_ATOMS   50000
#define N_EDGES   1600000
#define N_ANGLES  1500000
#define BT        192     // threads per angle-block (3 waves); hbuf = 48 KB -> 3 blocks/CU

__device__ __forceinline__ float silu_f(float x) {
    // x * sigmoid(x) = x / (1 + exp(-x)); fast div + hw exp
    return __fdividef(x, 1.0f + __expf(-x));
}

// ---------------------------------------------------------------------------
// Edge precompute: Rij[e] = (s/d, (s/d^2)*vec)  as float4
// ---------------------------------------------------------------------------
__global__ __launch_bounds__(256) void edge_kernel(
    const float* __restrict__ distances, const float* __restrict__ sw,
    const float* __restrict__ vec, float4* __restrict__ Rij)
{
    int e = (int)blockIdx.x * 256 + (int)threadIdx.x;
    if (e >= N_EDGES) return;
    const float d   = distances[e];
    const float s   = sw[e];
    const float inv = 1.0f / d;
    const float sij = s * inv;
    const float c   = sij * inv;
    const float vx = vec[3*e+0], vy = vec[3*e+1], vz = vec[3*e+2];
    Rij[e] = make_float4(sij, c*vx, c*vy, c*vz);
}

// ---------------------------------------------------------------------------
// CSR build: histogram -> single-block scan -> scatter (order sorted by atom)
// ---------------------------------------------------------------------------
__global__ __launch_bounds__(256) void hist_kernel(
    const int* __restrict__ a_ca, int* __restrict__ cnt)
{
    int i = (int)blockIdx.x * 256 + (int)threadIdx.x;
    if (i < N_ANGLES) atomicAdd(&cnt[a_ca[i]], 1);
}

__global__ __launch_bounds__(1024) void scan_kernel(
    const int* __restrict__ cnt, int* __restrict__ cursor)
{
    __shared__ int part[1024];
    const int tid = (int)threadIdx.x;
    const int CH = 49;                    // 1024*49 = 50176 >= N_ATOMS
    const int base = tid * CH;
    int s = 0;
    for (int k = 0; k < CH; ++k) {
        int idx = base + k;
        if (idx < N_ATOMS) s += cnt[idx];
    }
    part[tid] = s;
    __syncthreads();
    for (int off = 1; off < 1024; off <<= 1) {   // Hillis-Steele inclusive scan
        int v = (tid >= off) ? part[tid - off] : 0;
        __syncthreads();
        part[tid] += v;
        __syncthreads();
    }
    int run = (tid == 0) ? 0 : part[tid - 1];    // exclusive base for this chunk
    for (int k = 0; k < CH; ++k) {
        int idx = base + k;
        if (idx < N_ATOMS) { cursor[idx] = run; run += cnt[idx]; }
    }
}

__global__ __launch_bounds__(256) void scatter_kernel(
    const int* __restrict__ a_ca, int* __restrict__ cursor, int* __restrict__ order)
{
    int i = (int)blockIdx.x * 256 + (int)threadIdx.x;
    if (i < N_ANGLES) {
        int pos = atomicAdd(&cursor[a_ca[i]], 1);
        order[pos] = i;
    }
}

// ---------------------------------------------------------------------------
// Angle kernel: one thread per CSR position (angles sorted by central atom).
// MLP identical to R1 (one-hot collapse, shared W3). hbuf is XOR-swizzled so
// both the per-thread column access (MLP) and the cross-thread row access
// (segmented reduction) are bank-conflict-free.
// Reduction: contiguous runs of equal atom -> one atomicAdd per (segment, j)
// instead of per (angle, j): ~23x fewer global atomics.
// ---------------------------------------------------------------------------
__global__ __launch_bounds__(BT, 2) void angle_kernel(
    const int* __restrict__ order,
    const int* __restrict__ a_src, const int* __restrict__ a_dst,
    const int* __restrict__ a_ca, const float4* __restrict__ Rij,
    const int* __restrict__ edge_dst, const int* __restrict__ species,
    const float* __restrict__ W0, const float* __restrict__ b0,
    const float* __restrict__ W1, const float* __restrict__ b1,
    const float* __restrict__ W2, const float* __restrict__ b2,
    const float* __restrict__ W3, const float* __restrict__ b3,
    float* __restrict__ out)
{
    __shared__ float hbuf[64 * BT];     // 48 KB, [k][tid^(k&31)]
    __shared__ int   atomv[BT];
    __shared__ int   seg_start[BT];
    __shared__ int   nseg;

    const int tid = (int)threadIdx.x;
    const int i = (int)blockIdx.x * BT + tid;
    const bool active = (i < N_ANGLES);
    const int a = active ? order[i] : 0;

    if (tid == 0) nseg = 0;

    const int se = a_src[a];
    const int de = a_dst[a];
    const int ca = a_ca[a];
    atomv[tid] = active ? ca : -1;

    const float4 Rs = Rij[se];
    const float4 Rd = Rij[de];
    const float theta = Rs.x*Rd.x + Rs.y*Rd.y + Rs.z*Rd.z + Rs.w*Rd.w;
    const int ssp = species[edge_dst[se]];
    const int dsp = species[edge_dst[de]];

    float hs[64];   // MLP-1 final hidden, held across the m=1 pass

    #pragma unroll 1
    for (int m = 0; m < 2; ++m) {
        const int r1 = m ? dsp : ssp;
        const int r2 = m ? ssp : dsp;
        const float* __restrict__ rA = W0 + (1  + r1) * 64;
        const float* __restrict__ rB = W0 + (17 + r2) * 64;

        // layer 0 (one-hot collapsed)
        #pragma unroll
        for (int j = 0; j < 64; ++j) {
            float x = fmaf(theta, W0[j], rA[j] + rB[j] + b0[j]);
            hbuf[j*BT + (tid ^ (j & 31))] = silu_f(x);
        }

        // layers 1 and 2: dense 64x64, acc in registers, scalar weight loads
        #pragma unroll 1
        for (int l = 0; l < 2; ++l) {
            const float* __restrict__ W  = l ? W2 : W1;
            const float* __restrict__ bb = l ? b2 : b1;
            float nxt[64];
            #pragma unroll
            for (int j = 0; j < 64; ++j) nxt[j] = bb[j];
            #pragma unroll 2
            for (int k = 0; k < 64; ++k) {
                const float hk = hbuf[k*BT + (tid ^ (k & 31))];
                const float* __restrict__ wr = W + k*64;
                #pragma unroll
                for (int j = 0; j < 64; ++j) nxt[j] = fmaf(hk, wr[j], nxt[j]);
            }
            #pragma unroll
            for (int j = 0; j < 64; ++j) hbuf[j*BT + (tid ^ (j & 31))] = silu_f(nxt[j]);
        }

        if (m == 0) {
            #pragma unroll
            for (int j = 0; j < 64; ++j) hs[j] = hbuf[j*BT + (tid ^ (j & 31))];
        } else {
            #pragma unroll
            for (int j = 0; j < 64; ++j) hbuf[j*BT + (tid ^ (j & 31))] += hs[j];
        }
    }

    // shared final layer: G = (hfin1+hfin2) @ W3 + 2*b3
    float g[64];
    #pragma unroll
    for (int j = 0; j < 64; ++j) g[j] = 2.0f * b3[j];
    #pragma unroll 2
    for (int k = 0; k < 64; ++k) {
        const float hk = hbuf[k*BT + (tid ^ (k & 31))];
        const float* __restrict__ wr = W3 + k*64;
        #pragma unroll
        for (int j = 0; j < 64; ++j) g[j] = fmaf(hk, wr[j], g[j]);
    }

    // stash g*theta for the cross-thread reduction (own column only -> no sync yet)
    #pragma unroll
    for (int j = 0; j < 64; ++j)
        hbuf[j*BT + (tid ^ (j & 31))] = active ? g[j] * theta : 0.0f;
    __syncthreads();

    // segment heads register their start position (order within list irrelevant)
    if (active && (tid == 0 || atomv[tid] != atomv[tid-1])) {
        seg_start[atomicAdd(&nseg, 1)] = tid;
    }
    __syncthreads();

    const int NS = nseg;
    for (int w = tid; w < NS * 64; w += BT) {
        const int s  = w >> 6;
        const int j  = w & 63;
        const int st = seg_start[s];
        const int atom = atomv[st];
        float sum = 0.0f;
        for (int t = st; t < BT && atomv[t] == atom; ++t)
            sum += hbuf[j*BT + (t ^ (j & 31))];
        atomicAdd(out + (size_t)atom * 64 + j, sum);
    }
}

extern "C" void kernel_launch(void* const* d_in, const int* in_sizes, int n_in,
                              void* d_out, int out_size, void* d_ws, size_t ws_size,
                              hipStream_t stream) {
    const int*   species   = (const int*)  d_in[0];
    const int*   edge_dst  = (const int*)  d_in[1];
    const float* distances = (const float*)d_in[2];
    const float* sw        = (const float*)d_in[3];
    const float* vec       = (const float*)d_in[4];
    const int*   a_src     = (const int*)  d_in[5];
    const int*   a_dst     = (const int*)  d_in[6];
    const int*   a_ca      = (const int*)  d_in[7];
    const float* W0 = (const float*)d_in[8];
    const float* b0 = (const float*)d_in[9];
    const float* W1 = (const float*)d_in[10];
    const float* b1 = (const float*)d_in[11];
    const float* W2 = (const float*)d_in[12];
    const float* b2 = (const float*)d_in[13];
    const float* W3 = (const float*)d_in[14];
    const float* b3 = (const float*)d_in[15];
    float* out = (float*)d_out;

    // workspace layout: Rij | cnt | cursor | order  (~32 MB total)
    float4* Rij    = (float4*)d_ws;
    int*    cnt    = (int*)(Rij + N_EDGES);
    int*    cursor = cnt + N_ATOMS;
    int*    order  = cursor + N_ATOMS;

    hipMemsetAsync(d_out, 0, (size_t)out_size * sizeof(float), stream);
    hipMemsetAsync(cnt, 0, (size_t)N_ATOMS * sizeof(int), stream);

    edge_kernel<<<(N_EDGES + 255) / 256, 256, 0, stream>>>(distances, sw, vec, Rij);
    hist_kernel<<<(N_ANGLES + 255) / 256, 256, 0, stream>>>(a_ca, cnt);
    scan_kernel<<<1, 1024, 0, stream>>>(cnt, cursor);
    scatter_kernel<<<(N_ANGLES + 255) / 256, 256, 0, stream>>>(a_ca, cursor, order);

    angle_kernel<<<(N_ANGLES + BT - 1) / BT, BT, 0, stream>>>(
        order, a_src, a_dst, a_ca, Rij, edge_dst, species,
        W0, b0, W1, b1, W2, b2, W3, b3, out);
}

// Round 3
// 1131.236 us; speedup vs baseline: 4.7546x; 3.2054x over previous
//
#include <hip/hip_runtime.h>

#define N_ATOMS   50000
#define N_EDGES   1600000
#define N_ANGLES  1500000

typedef unsigned short u16;
typedef _Float16 f16x8 __attribute__((ext_vector_type(8)));
typedef float    f32x4 __attribute__((ext_vector_type(4)));
typedef u16      u16x8 __attribute__((ext_vector_type(8)));

__device__ __forceinline__ float silu_f(float x) {
    return __fdividef(x, 1.0f + __expf(-x));
}
__device__ __forceinline__ u16 f2h(float x) {
    _Float16 h = (_Float16)x;
    return __builtin_bit_cast(u16, h);
}
__device__ __forceinline__ float h2f(u16 u) {
    return (float)__builtin_bit_cast(_Float16, u);
}

// ---------------------------------------------------------------------------
// Edge precompute: Rij[e] = (s/d, (s/d^2)*vec)
// ---------------------------------------------------------------------------
__global__ __launch_bounds__(256) void edge_kernel(
    const float* __restrict__ distances, const float* __restrict__ sw,
    const float* __restrict__ vec, float4* __restrict__ Rij)
{
    int e = (int)blockIdx.x * 256 + (int)threadIdx.x;
    if (e >= N_EDGES) return;
    const float d   = distances[e];
    const float s   = sw[e];
    const float inv = 1.0f / d;
    const float sij = s * inv;
    const float c   = sij * inv;
    Rij[e] = make_float4(sij, c*vec[3*e+0], c*vec[3*e+1], c*vec[3*e+2]);
}

// ---------------------------------------------------------------------------
// Prep: WTl[n][k] = f16(Wl[k][n])  (B-fragments become contiguous 16B reads)
//       base_tab[s*16+d][j] = W0[1+s][j] + W0[17+d][j] + b0[j]
// ---------------------------------------------------------------------------
__global__ __launch_bounds__(256) void prep_kernel(
    const float* __restrict__ W0, const float* __restrict__ b0,
    const float* __restrict__ W1, const float* __restrict__ W2,
    const float* __restrict__ W3,
    u16* __restrict__ WT1, u16* __restrict__ WT2, u16* __restrict__ WT3,
    float* __restrict__ base_tab)
{
    int t = (int)blockIdx.x * 256 + (int)threadIdx.x;
    if (t < 3 * 4096) {
        int l = t >> 12, e = t & 4095, n = e >> 6, k = e & 63;
        const float* W = (l == 0) ? W1 : (l == 1) ? W2 : W3;
        u16* WT        = (l == 0) ? WT1 : (l == 1) ? WT2 : WT3;
        WT[n*64 + k] = f2h(W[k*64 + n]);
    }
    int u = t - 3 * 4096;
    if (u >= 0 && u < 256 * 64) {
        int sd = u >> 6, j = u & 63, s = sd >> 4, d = sd & 15;
        base_tab[u] = W0[(1+s)*64 + j] + W0[(17+d)*64 + j] + b0[j];
    }
}

// ---------------------------------------------------------------------------
// CSR build: histogram -> single-block scan -> scatter
// ---------------------------------------------------------------------------
__global__ __launch_bounds__(256) void hist_kernel(
    const int* __restrict__ a_ca, int* __restrict__ cnt)
{
    int i = (int)blockIdx.x * 256 + (int)threadIdx.x;
    if (i < N_ANGLES) atomicAdd(&cnt[a_ca[i]], 1);
}

__global__ __launch_bounds__(1024) void scan_kernel(
    const int* __restrict__ cnt, int* __restrict__ cursor)
{
    __shared__ int part[1024];
    const int tid = (int)threadIdx.x;
    const int CH = 49;
    const int base = tid * CH;
    int s = 0;
    for (int k = 0; k < CH; ++k) {
        int idx = base + k;
        if (idx < N_ATOMS) s += cnt[idx];
    }
    part[tid] = s;
    __syncthreads();
    for (int off = 1; off < 1024; off <<= 1) {
        int v = (tid >= off) ? part[tid - off] : 0;
        __syncthreads();
        part[tid] += v;
        __syncthreads();
    }
    int run = (tid == 0) ? 0 : part[tid - 1];
    for (int k = 0; k < CH; ++k) {
        int idx = base + k;
        if (idx < N_ATOMS) { cursor[idx] = run; run += cnt[idx]; }
    }
}

__global__ __launch_bounds__(256) void scatter_kernel(
    const int* __restrict__ a_ca, int* __restrict__ cursor, int* __restrict__ order)
{
    int i = (int)blockIdx.x * 256 + (int)threadIdx.x;
    if (i < N_ANGLES) {
        int pos = atomicAdd(&cursor[a_ca[i]], 1);
        order[pos] = i;
    }
}

// ---------------------------------------------------------------------------
// MFMA helpers. LDS act tile [64 rows(angles)][64 cols(feat)] f16, XOR-swizzled
// at 16B granularity: u16 index = row*64 + (col ^ ((row&7)<<3)).
// A frag (16x16x32): lane l -> row = mt*16 + (l&15), k = kt*32 + (l>>4)*8 .. +8
// B frag            : lane l -> n   = nt*16 + (l&15), k = kt*32 + (l>>4)*8 .. +8
// D                 : lane l -> col = nt*16 + (l&15), row = mt*16 + (l>>4)*4 + r
// ---------------------------------------------------------------------------
__device__ __forceinline__ void dense_mfma(const u16* __restrict__ strip,
    const u16* __restrict__ WT, int r15, int g4, f32x4 acc[4][4])
{
    #pragma unroll
    for (int kt = 0; kt < 2; ++kt) {
        f16x8 A[4], B[4];
        #pragma unroll
        for (int mt = 0; mt < 4; ++mt) {
            int row = mt*16 + r15;
            int col = (kt*32 + g4*8) ^ ((row & 7) << 3);
            A[mt] = *(const f16x8*)&strip[row*64 + col];
        }
        #pragma unroll
        for (int nt = 0; nt < 4; ++nt)
            B[nt] = *(const f16x8*)&WT[(nt*16 + r15)*64 + kt*32 + g4*8];
        #pragma unroll
        for (int mt = 0; mt < 4; ++mt) {
            #pragma unroll
            for (int nt = 0; nt < 4; ++nt)
                acc[mt][nt] = __builtin_amdgcn_mfma_f32_16x16x32_f16(
                    A[mt], B[nt], acc[mt][nt], 0, 0, 0);
        }
    }
}

__device__ __forceinline__ void act_store(u16* __restrict__ strip,
    const float* __restrict__ bias, int r15, int g4, f32x4 acc[4][4])
{
    float bn[4];
    #pragma unroll
    for (int nt = 0; nt < 4; ++nt) bn[nt] = bias[nt*16 + r15];
    #pragma unroll
    for (int mt = 0; mt < 4; ++mt) {
        #pragma unroll
        for (int r = 0; r < 4; ++r) {
            int row = mt*16 + g4*4 + r;
            int rsw = (row & 7) << 3;
            #pragma unroll
            for (int nt = 0; nt < 4; ++nt)
                strip[row*64 + ((nt*16 + r15) ^ rsw)] =
                    f2h(silu_f(acc[mt][nt][r] + bn[nt]));
        }
    }
}

// ---------------------------------------------------------------------------
// Angle kernel: 256 threads = 4 waves, each wave owns a 64-angle strip.
// MLP phase is barrier-free (wave-private LDS strips, same-wave DS ordering).
// L3 runs twice accumulating both passes into accG (init 2*b3) -> no h2 save.
// Scatter: CSR segmented reduction (R2), reading g*theta f16 from act area.
// ---------------------------------------------------------------------------
__global__ __launch_bounds__(256) void angle_kernel(
    const int* __restrict__ order,
    const int* __restrict__ a_src, const int* __restrict__ a_dst,
    const int* __restrict__ a_ca, const float4* __restrict__ Rij,
    const int* __restrict__ edge_dst, const int* __restrict__ species,
    const float* __restrict__ W0, const float* __restrict__ base_tab,
    const u16* __restrict__ WT1, const u16* __restrict__ WT2,
    const u16* __restrict__ WT3,
    const float* __restrict__ b1, const float* __restrict__ b2,
    const float* __restrict__ b3,
    float* __restrict__ out)
{
    __shared__ __align__(16) u16 act[256 * 64];   // 32 KB: 4 strips / red buffer
    __shared__ float theta_s[256];
    __shared__ int   atomv[256];
    __shared__ int   seg_start[256];
    __shared__ int   nseg;

    const int tid  = (int)threadIdx.x;
    const int lane = tid & 63;
    const int wv   = tid >> 6;
    const int r15  = lane & 15;
    const int g4   = lane >> 4;

    const int i = (int)blockIdx.x * 256 + tid;
    const bool active = (i < N_ANGLES);
    const int a = order[active ? i : 0];

    if (tid == 0) nseg = 0;

    const int se = a_src[a], de = a_dst[a], ca = a_ca[a];
    const float4 Rs = Rij[se], Rd = Rij[de];
    const float theta = Rs.x*Rd.x + Rs.y*Rd.y + Rs.z*Rd.z + Rs.w*Rd.w;
    const int ssp = species[edge_dst[se]];
    const int dsp = species[edge_dst[de]];

    atomv[tid]   = active ? ca : -1;
    theta_s[tid] = active ? theta : 0.0f;   // 0 theta zeroes tail contributions

    u16* strip = act + wv * 4096;

    // persistent G accumulator: G = h2a@W3 + h2b@W3 + 2*b3
    f32x4 accG[4][4];
    #pragma unroll
    for (int nt = 0; nt < 4; ++nt) {
        float bv = 2.0f * b3[nt*16 + r15];
        #pragma unroll
        for (int mt = 0; mt < 4; ++mt) accG[mt][nt] = {bv, bv, bv, bv};
    }

    #pragma unroll 1
    for (int m = 0; m < 2; ++m) {
        // ---- layer 0 (one-hot collapsed): thread's own row = lane
        {
            const int pair = m ? (dsp*16 + ssp) : (ssp*16 + dsp);
            const float4* bs4 = (const float4*)(base_tab + pair*64);
            const float4* w04 = (const float4*)W0;     // row 0, wave-uniform
            const int rsw = (lane & 7) << 3;
            #pragma unroll
            for (int c = 0; c < 8; ++c) {
                float4 bl = bs4[2*c], bh = bs4[2*c+1];
                float4 wl = w04[2*c], wh = w04[2*c+1];
                u16x8 hv;
                hv[0] = f2h(silu_f(fmaf(theta, wl.x, bl.x)));
                hv[1] = f2h(silu_f(fmaf(theta, wl.y, bl.y)));
                hv[2] = f2h(silu_f(fmaf(theta, wl.z, bl.z)));
                hv[3] = f2h(silu_f(fmaf(theta, wl.w, bl.w)));
                hv[4] = f2h(silu_f(fmaf(theta, wh.x, bh.x)));
                hv[5] = f2h(silu_f(fmaf(theta, wh.y, bh.y)));
                hv[6] = f2h(silu_f(fmaf(theta, wh.z, bh.z)));
                hv[7] = f2h(silu_f(fmaf(theta, wh.w, bh.w)));
                *(u16x8*)&strip[lane*64 + ((c*8) ^ rsw)] = hv;
            }
        }

        // ---- layer 1
        {
            f32x4 acc[4][4];
            #pragma unroll
            for (int mt = 0; mt < 4; ++mt)
                #pragma unroll
                for (int nt = 0; nt < 4; ++nt) acc[mt][nt] = {0.f, 0.f, 0.f, 0.f};
            dense_mfma(strip, WT1, r15, g4, acc);
            act_store(strip, b1, r15, g4, acc);
        }
        // ---- layer 2
        {
            f32x4 acc[4][4];
            #pragma unroll
            for (int mt = 0; mt < 4; ++mt)
                #pragma unroll
                for (int nt = 0; nt < 4; ++nt) acc[mt][nt] = {0.f, 0.f, 0.f, 0.f};
            dense_mfma(strip, WT2, r15, g4, acc);
            act_store(strip, b2, r15, g4, acc);
        }
        // ---- layer 3: accumulate into persistent accG
        dense_mfma(strip, WT3, r15, g4, accG);
    }

    // write g*theta (f16) into the act area, now a [256 angles][64] red buffer
    #pragma unroll
    for (int mt = 0; mt < 4; ++mt) {
        #pragma unroll
        for (int r = 0; r < 4; ++r) {
            int row = mt*16 + g4*4 + r;
            float th = theta_s[wv*64 + row];
            int rsw = (row & 7) << 3;
            #pragma unroll
            for (int nt = 0; nt < 4; ++nt)
                strip[row*64 + ((nt*16 + r15) ^ rsw)] = f2h(accG[mt][nt][r] * th);
        }
    }
    __syncthreads();

    // CSR segmented reduction: one atomicAdd per (segment, feature)
    if (active && (tid == 0 || atomv[tid] != atomv[tid-1]))
        seg_start[atomicAdd(&nseg, 1)] = tid;
    __syncthreads();

    const int NS = nseg;
    for (int wk = tid; wk < NS * 64; wk += 256) {
        int s  = wk >> 6, j = wk & 63;
        int st = seg_start[s];
        int atom = atomv[st];
        float sum = 0.0f;
        for (int t = st; t < 256 && atomv[t] == atom; ++t)
            sum += h2f(act[t*64 + (j ^ ((t & 7) << 3))]);
        atomicAdd(out + (size_t)atom*64 + j, sum);
    }
}

extern "C" void kernel_launch(void* const* d_in, const int* in_sizes, int n_in,
                              void* d_out, int out_size, void* d_ws, size_t ws_size,
                              hipStream_t stream) {
    const int*   species   = (const int*)  d_in[0];
    const int*   edge_dst  = (const int*)  d_in[1];
    const float* distances = (const float*)d_in[2];
    const float* sw        = (const float*)d_in[3];
    const float* vec       = (const float*)d_in[4];
    const int*   a_src     = (const int*)  d_in[5];
    const int*   a_dst     = (const int*)  d_in[6];
    const int*   a_ca      = (const int*)  d_in[7];
    const float* W0 = (const float*)d_in[8];
    const float* b0 = (const float*)d_in[9];
    const float* W1 = (const float*)d_in[10];
    const float* b1 = (const float*)d_in[11];
    const float* W2 = (const float*)d_in[12];
    const float* b2 = (const float*)d_in[13];
    const float* W3 = (const float*)d_in[14];
    const float* b3 = (const float*)d_in[15];
    float* out = (float*)d_out;

    // ws: Rij(25.6M) | cnt(0.2M) | cursor(0.2M) | order(6M) | WT1/2/3 | base_tab
    float4* Rij    = (float4*)d_ws;
    int*    cnt    = (int*)(Rij + N_EDGES);
    int*    cursor = cnt + N_ATOMS;
    int*    order  = cursor + N_ATOMS;
    u16*    WT1    = (u16*)(order + N_ANGLES);
    u16*    WT2    = WT1 + 4096;
    u16*    WT3    = WT2 + 4096;
    float*  base_tab = (float*)(WT3 + 4096);

    hipMemsetAsync(d_out, 0, (size_t)out_size * sizeof(float), stream);
    hipMemsetAsync(cnt, 0, (size_t)N_ATOMS * sizeof(int), stream);

    edge_kernel<<<(N_EDGES + 255) / 256, 256, 0, stream>>>(distances, sw, vec, Rij);
    prep_kernel<<<(3*4096 + 256*64 + 255) / 256, 256, 0, stream>>>(
        W0, b0, W1, W2, W3, WT1, WT2, WT3, base_tab);
    hist_kernel<<<(N_ANGLES + 255) / 256, 256, 0, stream>>>(a_ca, cnt);
    scan_kernel<<<1, 1024, 0, stream>>>(cnt, cursor);
    scatter_kernel<<<(N_ANGLES + 255) / 256, 256, 0, stream>>>(a_ca, cursor, order);

    angle_kernel<<<(N_ANGLES + 255) / 256, 256, 0, stream>>>(
        order, a_src, a_dst, a_ca, Rij, edge_dst, species,
        W0, base_tab, WT1, WT2, WT3, b1, b2, b3, out);
}

// Round 4
// 1047.002 us; speedup vs baseline: 5.1372x; 1.0805x over previous
//
#include <hip/hip_runtime.h>

#define N_ATOMS   50000
#define N_EDGES   1600000
#define N_ANGLES  1500000

typedef unsigned short u16;
typedef _Float16 f16x8 __attribute__((ext_vector_type(8)));
typedef float    f32x4 __attribute__((ext_vector_type(4)));
typedef u16      u16x8 __attribute__((ext_vector_type(8)));

__device__ __forceinline__ float silu_f(float x) {
    return __fdividef(x, 1.0f + __expf(-x));
}
__device__ __forceinline__ u16 f2h(float x) {
    _Float16 h = (_Float16)x;
    return __builtin_bit_cast(u16, h);
}
__device__ __forceinline__ float h2f(u16 u) {
    return (float)__builtin_bit_cast(_Float16, u);
}

// ---------------------------------------------------------------------------
// Edge precompute: Rij[e] = (s/d, (s/d^2)*vec)
// ---------------------------------------------------------------------------
__global__ __launch_bounds__(256) void edge_kernel(
    const float* __restrict__ distances, const float* __restrict__ sw,
    const float* __restrict__ vec, float4* __restrict__ Rij)
{
    int e = (int)blockIdx.x * 256 + (int)threadIdx.x;
    if (e >= N_EDGES) return;
    const float d   = distances[e];
    const float s   = sw[e];
    const float inv = 1.0f / d;
    const float sij = s * inv;
    const float c   = sij * inv;
    Rij[e] = make_float4(sij, c*vec[3*e+0], c*vec[3*e+1], c*vec[3*e+2]);
}

// ---------------------------------------------------------------------------
// Prep: WTl[n][k] = f16(Wl[k][n]);  base_tab[s*16+d][j] = W0[1+s][j]+W0[17+d][j]+b0[j]
// ---------------------------------------------------------------------------
__global__ __launch_bounds__(256) void prep_kernel(
    const float* __restrict__ W0, const float* __restrict__ b0,
    const float* __restrict__ W1, const float* __restrict__ W2,
    const float* __restrict__ W3,
    u16* __restrict__ WT1, u16* __restrict__ WT2, u16* __restrict__ WT3,
    float* __restrict__ base_tab)
{
    int t = (int)blockIdx.x * 256 + (int)threadIdx.x;
    if (t < 3 * 4096) {
        int l = t >> 12, e = t & 4095, n = e >> 6, k = e & 63;
        const float* W = (l == 0) ? W1 : (l == 1) ? W2 : W3;
        u16* WT        = (l == 0) ? WT1 : (l == 1) ? WT2 : WT3;
        WT[n*64 + k] = f2h(W[k*64 + n]);
    }
    int u = t - 3 * 4096;
    if (u >= 0 && u < 256 * 64) {
        int sd = u >> 6, j = u & 63, s = sd >> 4, d = sd & 15;
        base_tab[u] = W0[(1+s)*64 + j] + W0[(17+d)*64 + j] + b0[j];
    }
}

// ---------------------------------------------------------------------------
// CSR build: histogram -> single-block scan -> fused gather+scatter
// ---------------------------------------------------------------------------
__global__ __launch_bounds__(256) void hist_kernel(
    const int* __restrict__ a_ca, int* __restrict__ cnt)
{
    int i = (int)blockIdx.x * 256 + (int)threadIdx.x;
    if (i < N_ANGLES) atomicAdd(&cnt[a_ca[i]], 1);
}

__global__ __launch_bounds__(1024) void scan_kernel(
    const int* __restrict__ cnt, int* __restrict__ cursor)
{
    __shared__ int part[1024];
    const int tid = (int)threadIdx.x;
    const int CH = 49;
    const int base = tid * CH;
    int s = 0;
    for (int k = 0; k < CH; ++k) {
        int idx = base + k;
        if (idx < N_ATOMS) s += cnt[idx];
    }
    part[tid] = s;
    __syncthreads();
    for (int off = 1; off < 1024; off <<= 1) {
        int v = (tid >= off) ? part[tid - off] : 0;
        __syncthreads();
        part[tid] += v;
        __syncthreads();
    }
    int run = (tid == 0) ? 0 : part[tid - 1];
    for (int k = 0; k < CH; ++k) {
        int idx = base + k;
        if (idx < N_ATOMS) { cursor[idx] = run; run += cnt[idx]; }
    }
}

// All random gathers live HERE (high-occupancy, latency hidden by TLP).
// Writes a packed, atom-sorted 16B record per angle: {theta, pair, ca, 0}.
__global__ __launch_bounds__(256) void scatter_kernel(
    const int* __restrict__ a_src, const int* __restrict__ a_dst,
    const int* __restrict__ a_ca, const float4* __restrict__ Rij,
    const int* __restrict__ edge_dst, const int* __restrict__ species,
    int* __restrict__ cursor, float4* __restrict__ rec)
{
    int i = (int)blockIdx.x * 256 + (int)threadIdx.x;
    if (i >= N_ANGLES) return;
    const int se = a_src[i], de = a_dst[i], ca = a_ca[i];
    const float4 Rs = Rij[se], Rd = Rij[de];
    const float theta = Rs.x*Rd.x + Rs.y*Rd.y + Rs.z*Rd.z + Rs.w*Rd.w;
    const int ssp = species[edge_dst[se]];
    const int dsp = species[edge_dst[de]];
    const int pos = atomicAdd(&cursor[ca], 1);
    rec[pos] = make_float4(theta, __int_as_float(ssp*16 + dsp),
                           __int_as_float(ca), 0.0f);
}

// ---------------------------------------------------------------------------
// Angle kernel: 4 waves x 64-angle strips; input = ONE coalesced record stream.
// MLP phase barrier-free (wave-private LDS strips). L3 runs twice into accG
// (init 2*b3). Scatter: CSR segmented reduction with u16x8 vector reads.
// act tile [row][col^((row&7)<<3)] u16 -> conflict-free for MLP & reduction.
// ---------------------------------------------------------------------------
__global__ __launch_bounds__(256) void angle_kernel(
    const float4* __restrict__ rec,
    const float* __restrict__ W0, const float* __restrict__ base_tab,
    const u16* __restrict__ WT1, const u16* __restrict__ WT2,
    const u16* __restrict__ WT3,
    const float* __restrict__ b1, const float* __restrict__ b2,
    const float* __restrict__ b3,
    float* __restrict__ out)
{
    __shared__ __align__(16) u16 act[256 * 64];   // 32 KB
    __shared__ float theta_s[256];
    __shared__ int   atomv[256];
    __shared__ int   seg_start[256];
    __shared__ int   nseg;

    const int tid  = (int)threadIdx.x;
    const int lane = tid & 63;
    const int wv   = tid >> 6;
    const int r15  = lane & 15;
    const int g4   = lane >> 4;

    const int i = (int)blockIdx.x * 256 + tid;
    const bool active = (i < N_ANGLES);
    const float4 rv = rec[active ? i : 0];

    const float theta = active ? rv.x : 0.0f;
    const int   pair  = __float_as_int(rv.y);
    const int   ca    = active ? __float_as_int(rv.z) : -1;

    if (tid == 0) nseg = 0;
    atomv[tid]   = ca;
    theta_s[tid] = theta;

    u16* strip = act + wv * 4096;

    // persistent G accumulator: G = h2a@W3 + h2b@W3 + 2*b3
    f32x4 accG[4][4];
    #pragma unroll
    for (int nt = 0; nt < 4; ++nt) {
        float bv = 2.0f * b3[nt*16 + r15];
        #pragma unroll
        for (int mt = 0; mt < 4; ++mt) accG[mt][nt] = {bv, bv, bv, bv};
    }

    #pragma unroll 1
    for (int m = 0; m < 2; ++m) {
        // ---- layer 0 (one-hot collapsed): thread's own row = lane
        {
            const int p = m ? (((pair & 15) << 4) | (pair >> 4)) : pair;
            const float4* bs4 = (const float4*)(base_tab + p*64);
            const float4* w04 = (const float4*)W0;     // row 0, wave-uniform
            const int rsw = (lane & 7) << 3;
            #pragma unroll
            for (int c = 0; c < 8; ++c) {
                float4 bl = bs4[2*c], bh = bs4[2*c+1];
                float4 wl = w04[2*c], wh = w04[2*c+1];
                u16x8 hv;
                hv[0] = f2h(silu_f(fmaf(theta, wl.x, bl.x)));
                hv[1] = f2h(silu_f(fmaf(theta, wl.y, bl.y)));
                hv[2] = f2h(silu_f(fmaf(theta, wl.z, bl.z)));
                hv[3] = f2h(silu_f(fmaf(theta, wl.w, bl.w)));
                hv[4] = f2h(silu_f(fmaf(theta, wh.x, bh.x)));
                hv[5] = f2h(silu_f(fmaf(theta, wh.y, bh.y)));
                hv[6] = f2h(silu_f(fmaf(theta, wh.z, bh.z)));
                hv[7] = f2h(silu_f(fmaf(theta, wh.w, bh.w)));
                *(u16x8*)&strip[lane*64 + ((c*8) ^ rsw)] = hv;
            }
        }

        // ---- layers 1..3 (MFMA). kt x {A-frag, B-frag, 16 mfma}.
        #pragma unroll 1
        for (int l = 0; l < 3; ++l) {
            const u16* WT = (l == 0) ? WT1 : (l == 1) ? WT2 : WT3;
            f32x4 accL[4][4];
            f32x4 (&acc)[4][4] = (l == 2) ? accG : accL;
            if (l < 2) {
                #pragma unroll
                for (int mt = 0; mt < 4; ++mt)
                    #pragma unroll
                    for (int nt = 0; nt < 4; ++nt) accL[mt][nt] = {0.f,0.f,0.f,0.f};
            }
            #pragma unroll
            for (int kt = 0; kt < 2; ++kt) {
                f16x8 A[4], B[4];
                #pragma unroll
                for (int mt = 0; mt < 4; ++mt) {
                    int row = mt*16 + r15;
                    int col = (kt*32 + g4*8) ^ ((row & 7) << 3);
                    A[mt] = *(const f16x8*)&strip[row*64 + col];
                }
                #pragma unroll
                for (int nt = 0; nt < 4; ++nt)
                    B[nt] = *(const f16x8*)&WT[(nt*16 + r15)*64 + kt*32 + g4*8];
                #pragma unroll
                for (int mt = 0; mt < 4; ++mt)
                    #pragma unroll
                    for (int nt = 0; nt < 4; ++nt)
                        acc[mt][nt] = __builtin_amdgcn_mfma_f32_16x16x32_f16(
                            A[mt], B[nt], acc[mt][nt], 0, 0, 0);
            }
            if (l < 2) {   // bias + silu + store back to strip
                const float* bias = (l == 0) ? b1 : b2;
                float bn[4];
                #pragma unroll
                for (int nt = 0; nt < 4; ++nt) bn[nt] = bias[nt*16 + r15];
                #pragma unroll
                for (int mt = 0; mt < 4; ++mt) {
                    #pragma unroll
                    for (int r = 0; r < 4; ++r) {
                        int row = mt*16 + g4*4 + r;
                        int rsw = (row & 7) << 3;
                        #pragma unroll
                        for (int nt = 0; nt < 4; ++nt)
                            strip[row*64 + ((nt*16 + r15) ^ rsw)] =
                                f2h(silu_f(accL[mt][nt][r] + bn[nt]));
                    }
                }
            }
        }
    }

    // write g*theta (f16) into act, now a [256 angles][64 feat] red buffer
    #pragma unroll
    for (int mt = 0; mt < 4; ++mt) {
        #pragma unroll
        for (int r = 0; r < 4; ++r) {
            int row = mt*16 + g4*4 + r;
            float th = theta_s[wv*64 + row];
            int rsw = (row & 7) << 3;
            #pragma unroll
            for (int nt = 0; nt < 4; ++nt)
                strip[row*64 + ((nt*16 + r15) ^ rsw)] = f2h(accG[mt][nt][r] * th);
        }
    }
    __syncthreads();

    // segment heads
    if (active && (tid == 0 || atomv[tid] != atomv[tid-1]))
        seg_start[atomicAdd(&nseg, 1)] = tid;
    __syncthreads();

    // CSR segmented reduction, vectorized: task = (segment, 8-feature chunk)
    const int NS = nseg;
    for (int w = tid; w < NS * 8; w += 256) {
        const int s  = w >> 3;
        const int j0 = (w & 7) * 8;
        const int st = seg_start[s];
        const int atom = atomv[st];
        float sum[8] = {0,0,0,0,0,0,0,0};
        for (int t = st; t < 256 && atomv[t] == atom; ++t) {
            u16x8 v = *(const u16x8*)&act[t*64 + (j0 ^ ((t & 7) << 3))];
            #pragma unroll
            for (int q = 0; q < 8; ++q) sum[q] += h2f(v[q]);
        }
        float* op = out + (size_t)atom * 64 + j0;
        #pragma unroll
        for (int q = 0; q < 8; ++q) atomicAdd(op + q, sum[q]);
    }
}

extern "C" void kernel_launch(void* const* d_in, const int* in_sizes, int n_in,
                              void* d_out, int out_size, void* d_ws, size_t ws_size,
                              hipStream_t stream) {
    const int*   species   = (const int*)  d_in[0];
    const int*   edge_dst  = (const int*)  d_in[1];
    const float* distances = (const float*)d_in[2];
    const float* sw        = (const float*)d_in[3];
    const float* vec       = (const float*)d_in[4];
    const int*   a_src     = (const int*)  d_in[5];
    const int*   a_dst     = (const int*)  d_in[6];
    const int*   a_ca      = (const int*)  d_in[7];
    const float* W0 = (const float*)d_in[8];
    const float* b0 = (const float*)d_in[9];
    const float* W1 = (const float*)d_in[10];
    const float* b1 = (const float*)d_in[11];
    const float* W2 = (const float*)d_in[12];
    const float* b2 = (const float*)d_in[13];
    const float* W3 = (const float*)d_in[14];
    const float* b3 = (const float*)d_in[15];
    float* out = (float*)d_out;

    // ws: Rij(25.6MB) | cnt | cursor | rec(24MB) | WT1/2/3 | base_tab  (~50MB)
    float4* Rij    = (float4*)d_ws;
    int*    cnt    = (int*)(Rij + N_EDGES);
    int*    cursor = cnt + N_ATOMS;
    float4* rec    = (float4*)(cursor + N_ATOMS);
    u16*    WT1    = (u16*)(rec + N_ANGLES);
    u16*    WT2    = WT1 + 4096;
    u16*    WT3    = WT2 + 4096;
    float*  base_tab = (float*)(WT3 + 4096);

    hipMemsetAsync(d_out, 0, (size_t)out_size * sizeof(float), stream);
    hipMemsetAsync(cnt, 0, (size_t)N_ATOMS * sizeof(int), stream);

    edge_kernel<<<(N_EDGES + 255) / 256, 256, 0, stream>>>(distances, sw, vec, Rij);
    prep_kernel<<<(3*4096 + 256*64 + 255) / 256, 256, 0, stream>>>(
        W0, b0, W1, W2, W3, WT1, WT2, WT3, base_tab);
    hist_kernel<<<(N_ANGLES + 255) / 256, 256, 0, stream>>>(a_ca, cnt);
    scan_kernel<<<1, 1024, 0, stream>>>(cnt, cursor);
    scatter_kernel<<<(N_ANGLES + 255) / 256, 256, 0, stream>>>(
        a_src, a_dst, a_ca, Rij, edge_dst, species, cursor, rec);

    angle_kernel<<<(N_ANGLES + 255) / 256, 256, 0, stream>>>(
        rec, W0, base_tab, WT1, WT2, WT3, b1, b2, b3, out);
}